// Round 3
// baseline (48.871 us; speedup 1.0000x reference)
//
#include <hip/hip_runtime.h>

__device__ __forceinline__ float lrelu(float v) { return v >= 0.f ? v : 0.01f * v; }

__device__ __forceinline__ unsigned long long shfl_down_u64(unsigned long long v, int off) {
    unsigned lo = (unsigned)(v & 0xffffffffu);
    unsigned hi = (unsigned)(v >> 32);
    lo = __shfl_down(lo, off, 64);
    hi = __shfl_down(hi, off, 64);
    return ((unsigned long long)hi << 32) | lo;
}

// One block (1024 threads = 16 waves) per batch element. Fully fused VAE forward. f32.
__global__ __launch_bounds__(1024) void vae_fused_kernel(
    const float* __restrict__ x,
    const float* __restrict__ eps,
    const float* __restrict__ emb,
    const float* __restrict__ w_e0, const float* __restrict__ b_e0,
    const float* __restrict__ w_e1, const float* __restrict__ b_e1,
    const float* __restrict__ w_mu, const float* __restrict__ b_mu,
    const float* __restrict__ w_lv, const float* __restrict__ b_lv,
    const float* __restrict__ w_d,  const float* __restrict__ b_d,
    const float* __restrict__ w_d0, const float* __restrict__ b_d0,
    const float* __restrict__ w_d1, const float* __restrict__ b_d1,
    const float* __restrict__ w_d2, const float* __restrict__ b_d2,
    float* __restrict__ out)
{
    const int b   = blockIdx.x;
    const int tid = threadIdx.x;

    __shared__ float h1s[50];
    __shared__ float zbuf[2][64];        // [0]=z_e, [1]=z_q
    __shared__ unsigned long long wkey[16];
    __shared__ int nmin_s;
    __shared__ float t0s[2][100];
    __shared__ float t1s[2][60];
    __shared__ float t2s[2][30];

    // ---------------- encode (tiny; waves 1-15 wait) ----------------
    if (tid < 50) {
        const float xv = x[b];
        float acc = b_e1[tid];
        #pragma unroll
        for (int i = 0; i < 10; ++i) {
            float h = lrelu(fmaf(xv, w_e0[i], b_e0[i]));
            acc = fmaf(h, w_e1[i * 50 + tid], acc);
        }
        h1s[tid] = lrelu(acc);
    }
    __syncthreads();
    if (tid < 64) {
        float mu = b_mu[tid];
        float lv = b_lv[tid];
        for (int i = 0; i < 50; ++i) {
            float h = h1s[i];
            mu = fmaf(h, w_mu[i * 64 + tid], mu);
            lv = fmaf(h, w_lv[i * 64 + tid], lv);
        }
        float z = fmaf(eps[b * 64 + tid], expf(0.5f * lv), mu);
        zbuf[0][tid] = z;
        out[b * 64 + tid] = z;                            // z_e
    }
    __syncthreads();

    // ---------------- SOM argmin over 4096 cells, 4 rows/thread ----------------
    float zr[64];
    #pragma unroll
    for (int i = 0; i < 64; ++i) zr[i] = zbuf[0][i];      // fully unrolled -> stays in VGPRs

    unsigned long long bestKey = ~0ull;
    #pragma unroll 1
    for (int it = 0; it < 4; ++it) {
        const int e = it * 1024 + tid;                    // all 4096 rows exactly once
        const float4* rp = reinterpret_cast<const float4*>(emb + e * 64);
        float acc = 0.f;
        #pragma unroll
        for (int c = 0; c < 16; ++c) {                    // same sequential fmaf order as
            float4 v = rp[c];                             // the passing round-2 kernel
            float d0 = v.x - zr[c * 4 + 0];
            float d1 = v.y - zr[c * 4 + 1];
            float d2 = v.z - zr[c * 4 + 2];
            float d3 = v.w - zr[c * 4 + 3];
            acc = fmaf(d0, d0, acc);
            acc = fmaf(d1, d1, acc);
            acc = fmaf(d2, d2, acc);
            acc = fmaf(d3, d3, acc);
        }
        // dist >= 0: float bits are order-preserving; low 32 = index -> first-occurrence
        // tie-break like jnp.argmin.
        unsigned long long key =
            ((unsigned long long)__float_as_uint(acc) << 32) | (unsigned)e;
        bestKey = key < bestKey ? key : bestKey;
    }
    // wave-level min reduce (6 butterfly steps), then 16-entry LDS combine
    #pragma unroll
    for (int off = 32; off > 0; off >>= 1) {
        unsigned long long o = shfl_down_u64(bestKey, off);
        bestKey = o < bestKey ? o : bestKey;
    }
    if ((tid & 63) == 0) wkey[tid >> 6] = bestKey;
    __syncthreads();
    if (tid < 16) {
        unsigned long long k = wkey[tid];
        #pragma unroll
        for (int off = 8; off > 0; off >>= 1) {
            unsigned long long o = shfl_down_u64(k, off);
            k = o < k ? o : k;
        }
        if (tid == 0) nmin_s = (int)(k & 0xffffffffu);
    }
    __syncthreads();
    const int nmin = nmin_s;
    const int nx = nmin >> 6, ny = nmin & 63;

    // ---------------- z_q + neighbors ----------------
    if (tid < 64) {
        const int j = tid;
        float zq = emb[nmin * 64 + j];
        zbuf[1][j] = zq;
        out[16384 + b * 64 + j] = zq;                     // z_q
        const int nb = 32768 + b * 320;                   // z_q_neighbors [B,5,64]
        out[nb + j] = zq;                                 // row 0: z_q
        float up = (nx < 63) ? emb[((nx + 1) * 64 + ny) * 64 + j] : 0.f;
        out[nb + 64 + j] = up;                            // row 1: up
        float dn = (nx > 0) ? emb[((nx - 1) * 64 + ny) * 64 + j] : 0.f;
        out[nb + 128 + j] = dn;                           // row 2: down
        out[nb + 192 + j] = 0.f;                          // row 3: right (faithful bug)
        float lf = (ny > 0) ? emb[(nx * 64 + (ny - 1)) * 64 + j] : 0.f;
        out[nb + 256 + j] = lf;                           // row 4: left
    }
    __syncthreads();

    // ---------------- decode: wave 0 -> z_e, wave 1 -> z_q ----------------
    const int w    = tid >> 6;
    const int lane = tid & 63;
    if (w < 2) {
        for (int j = lane; j < 100; j += 64) {
            float acc = b_d[j];
            for (int i = 0; i < 64; ++i)
                acc = fmaf(zbuf[w][i], w_d[i * 100 + j], acc);
            t0s[w][j] = lrelu(acc);
        }
    }
    __syncthreads();
    if (w < 2 && lane < 60) {
        float acc = b_d0[lane];
        for (int i = 0; i < 100; ++i)
            acc = fmaf(t0s[w][i], w_d0[i * 60 + lane], acc);
        t1s[w][lane] = lrelu(acc);
    }
    __syncthreads();
    if (w < 2 && lane < 30) {
        float acc = b_d1[lane];
        for (int i = 0; i < 60; ++i)
            acc = fmaf(t1s[w][i], w_d1[i * 30 + lane], acc);
        t2s[w][lane] = lrelu(acc);
    }
    __syncthreads();
    if (w < 2 && lane == 0) {
        float acc = b_d2[0];
        for (int i = 0; i < 30; ++i)
            acc = fmaf(t2s[w][i], w_d2[i], acc);
        float r = lrelu(acc);
        // decoder_e at 114688, decoder_q at 114944
        out[(w == 0 ? 114688 : 114944) + b] = r;
    }
}

extern "C" void kernel_launch(void* const* d_in, const int* in_sizes, int n_in,
                              void* d_out, int out_size, void* d_ws, size_t ws_size,
                              hipStream_t stream) {
    (void)in_sizes; (void)n_in; (void)d_ws; (void)ws_size; (void)out_size;
    const float* x    = (const float*)d_in[0];
    const float* eps  = (const float*)d_in[1];
    const float* emb  = (const float*)d_in[2];
    const float* w_e0 = (const float*)d_in[3];
    const float* b_e0 = (const float*)d_in[4];
    const float* w_e1 = (const float*)d_in[5];
    const float* b_e1 = (const float*)d_in[6];
    const float* w_mu = (const float*)d_in[7];
    const float* b_mu = (const float*)d_in[8];
    const float* w_lv = (const float*)d_in[9];
    const float* b_lv = (const float*)d_in[10];
    const float* w_d  = (const float*)d_in[11];
    const float* b_d  = (const float*)d_in[12];
    const float* w_d0 = (const float*)d_in[13];
    const float* b_d0 = (const float*)d_in[14];
    const float* w_d1 = (const float*)d_in[15];
    const float* b_d1 = (const float*)d_in[16];
    const float* w_d2 = (const float*)d_in[17];
    const float* b_d2 = (const float*)d_in[18];
    float* out = (float*)d_out;

    vae_fused_kernel<<<256, 1024, 0, stream>>>(
        x, eps, emb, w_e0, b_e0, w_e1, b_e1, w_mu, b_mu, w_lv, b_lv,
        w_d, b_d, w_d0, b_d0, w_d1, b_d1, w_d2, b_d2, out);
}

// Round 4
// 34.808 us; speedup vs baseline: 1.4040x; 1.4040x over previous
//
#include <hip/hip_runtime.h>

__device__ __forceinline__ float lrelu(float v) { return v >= 0.f ? v : 0.01f * v; }

__device__ __forceinline__ unsigned long long shfl_down_u64(unsigned long long v, int off) {
    unsigned lo = (unsigned)(v & 0xffffffffu);
    unsigned hi = (unsigned)(v >> 32);
    lo = __shfl_down(lo, off, 64);
    hi = __shfl_down(hi, off, 64);
    return ((unsigned long long)hi << 32) | lo;
}

// One block (1024 threads = 16 waves) per batch element. Fully fused VAE forward. f32.
__global__ __launch_bounds__(1024) void vae_fused_kernel(
    const float* __restrict__ x,
    const float* __restrict__ eps,
    const float* __restrict__ emb,
    const float* __restrict__ w_e0, const float* __restrict__ b_e0,
    const float* __restrict__ w_e1, const float* __restrict__ b_e1,
    const float* __restrict__ w_mu, const float* __restrict__ b_mu,
    const float* __restrict__ w_lv, const float* __restrict__ b_lv,
    const float* __restrict__ w_d,  const float* __restrict__ b_d,
    const float* __restrict__ w_d0, const float* __restrict__ b_d0,
    const float* __restrict__ w_d1, const float* __restrict__ b_d1,
    const float* __restrict__ w_d2, const float* __restrict__ b_d2,
    float* __restrict__ out)
{
    const int b   = blockIdx.x;
    const int tid = threadIdx.x;

    __shared__ float h1s[50];
    __shared__ __align__(16) float zbuf[2][64];   // [0]=z_e, [1]=z_q
    __shared__ unsigned long long wkey[16];
    __shared__ int nmin_s;
    __shared__ float t0s[2][100];
    __shared__ float t1s[2][60];
    __shared__ float t2s[2][30];

    // ---------------- encode (tiny; other waves wait) ----------------
    if (tid < 50) {
        const float xv = x[b];
        float acc = b_e1[tid];
        #pragma unroll
        for (int i = 0; i < 10; ++i) {
            float h = lrelu(fmaf(xv, w_e0[i], b_e0[i]));
            acc = fmaf(h, w_e1[i * 50 + tid], acc);
        }
        h1s[tid] = lrelu(acc);
    }
    __syncthreads();
    if (tid < 64) {
        float mu = b_mu[tid];
        float lv = b_lv[tid];
        for (int i = 0; i < 50; ++i) {
            float h = h1s[i];
            mu = fmaf(h, w_mu[i * 64 + tid], mu);
            lv = fmaf(h, w_lv[i * 64 + tid], lv);
        }
        float z = fmaf(eps[b * 64 + tid], expf(0.5f * lv), mu);
        zbuf[0][tid] = z;
        out[b * 64 + tid] = z;                            // z_e
    }
    __syncthreads();

    // ---------------- SOM argmin over 4096 cells, coalesced ----------------
    // Wave handles 256 rows in 4 chunks of 64. Within a chunk, group g covers
    // rows 4g..4g+3 (1 KB contiguous): lane l reads float4 #l -> 8 cache lines
    // per instruction (coalescing optimum). Lane's z-chunk: cols (lane&15)*4.
    const int wv   = tid >> 6;
    const int lane = tid & 63;
    const float4 zl = *reinterpret_cast<const float4*>(&zbuf[0][(lane & 15) * 4]);

    unsigned long long bestKey = ~0ull;
    #pragma unroll 1
    for (int chunk = 0; chunk < 4; ++chunk) {
        const int rowBase = wv * 256 + chunk * 64;
        const float* base = emb + rowBase * 64;
        #pragma unroll
        for (int g = 0; g < 16; ++g) {
            const float4 v = *reinterpret_cast<const float4*>(base + g * 256 + lane * 4);
            const float d0 = v.x - zl.x;
            const float d1 = v.y - zl.y;
            const float d2 = v.z - zl.z;
            const float d3 = v.w - zl.w;
            float p = fmaf(d0, d0, fmaf(d1, d1, fmaf(d2, d2, d3 * d3)));
            // butterfly over the 16 lanes sharing one row
            p += __shfl_xor(p, 1);
            p += __shfl_xor(p, 2);
            p += __shfl_xor(p, 4);
            p += __shfl_xor(p, 8);
            const int row = rowBase + g * 4 + (lane >> 4);
            // dist >= 0: float bits order-preserving; low 32 = row index ->
            // first-occurrence tie-break like jnp.argmin.
            const unsigned long long key =
                ((unsigned long long)__float_as_uint(p) << 32) | (unsigned)row;
            bestKey = key < bestKey ? key : bestKey;
        }
    }
    // wave-level min reduce, then 16-entry combine
    #pragma unroll
    for (int off = 32; off > 0; off >>= 1) {
        unsigned long long o = shfl_down_u64(bestKey, off);
        bestKey = o < bestKey ? o : bestKey;
    }
    if (lane == 0) wkey[wv] = bestKey;
    __syncthreads();
    if (tid < 16) {
        unsigned long long k = wkey[tid];
        #pragma unroll
        for (int off = 8; off > 0; off >>= 1) {
            unsigned long long o = shfl_down_u64(k, off);
            k = o < k ? o : k;
        }
        if (tid == 0) nmin_s = (int)(k & 0xffffffffu);
    }
    __syncthreads();
    const int nmin = nmin_s;
    const int nx = nmin >> 6, ny = nmin & 63;

    // ---------------- z_q + neighbors ----------------
    if (tid < 64) {
        const int j = tid;
        float zq = emb[nmin * 64 + j];
        zbuf[1][j] = zq;
        out[16384 + b * 64 + j] = zq;                     // z_q
        const int nb = 32768 + b * 320;                   // z_q_neighbors [B,5,64]
        out[nb + j] = zq;                                 // row 0: z_q
        float up = (nx < 63) ? emb[((nx + 1) * 64 + ny) * 64 + j] : 0.f;
        out[nb + 64 + j] = up;                            // row 1: up
        float dn = (nx > 0) ? emb[((nx - 1) * 64 + ny) * 64 + j] : 0.f;
        out[nb + 128 + j] = dn;                           // row 2: down
        out[nb + 192 + j] = 0.f;                          // row 3: right (faithful bug)
        float lf = (ny > 0) ? emb[(nx * 64 + (ny - 1)) * 64 + j] : 0.f;
        out[nb + 256 + j] = lf;                           // row 4: left
    }
    __syncthreads();

    // ---------------- decode: wave 0 -> z_e, wave 1 -> z_q ----------------
    if (wv < 2) {
        for (int j = lane; j < 100; j += 64) {
            float acc = b_d[j];
            for (int i = 0; i < 64; ++i)
                acc = fmaf(zbuf[wv][i], w_d[i * 100 + j], acc);
            t0s[wv][j] = lrelu(acc);
        }
    }
    __syncthreads();
    if (wv < 2 && lane < 60) {
        float acc = b_d0[lane];
        for (int i = 0; i < 100; ++i)
            acc = fmaf(t0s[wv][i], w_d0[i * 60 + lane], acc);
        t1s[wv][lane] = lrelu(acc);
    }
    __syncthreads();
    if (wv < 2 && lane < 30) {
        float acc = b_d1[lane];
        for (int i = 0; i < 60; ++i)
            acc = fmaf(t1s[wv][i], w_d1[i * 30 + lane], acc);
        t2s[wv][lane] = lrelu(acc);
    }
    __syncthreads();
    if (wv < 2 && lane == 0) {
        float acc = b_d2[0];
        for (int i = 0; i < 30; ++i)
            acc = fmaf(t2s[wv][i], w_d2[i], acc);
        float r = lrelu(acc);
        // decoder_e at 114688, decoder_q at 114944
        out[(wv == 0 ? 114688 : 114944) + b] = r;
    }
}

extern "C" void kernel_launch(void* const* d_in, const int* in_sizes, int n_in,
                              void* d_out, int out_size, void* d_ws, size_t ws_size,
                              hipStream_t stream) {
    (void)in_sizes; (void)n_in; (void)d_ws; (void)ws_size; (void)out_size;
    const float* x    = (const float*)d_in[0];
    const float* eps  = (const float*)d_in[1];
    const float* emb  = (const float*)d_in[2];
    const float* w_e0 = (const float*)d_in[3];
    const float* b_e0 = (const float*)d_in[4];
    const float* w_e1 = (const float*)d_in[5];
    const float* b_e1 = (const float*)d_in[6];
    const float* w_mu = (const float*)d_in[7];
    const float* b_mu = (const float*)d_in[8];
    const float* w_lv = (const float*)d_in[9];
    const float* b_lv = (const float*)d_in[10];
    const float* w_d  = (const float*)d_in[11];
    const float* b_d  = (const float*)d_in[12];
    const float* w_d0 = (const float*)d_in[13];
    const float* b_d0 = (const float*)d_in[14];
    const float* w_d1 = (const float*)d_in[15];
    const float* b_d1 = (const float*)d_in[16];
    const float* w_d2 = (const float*)d_in[17];
    const float* b_d2 = (const float*)d_in[18];
    float* out = (float*)d_out;

    vae_fused_kernel<<<256, 1024, 0, stream>>>(
        x, eps, emb, w_e0, b_e0, w_e1, b_e1, w_mu, b_mu, w_lv, b_lv,
        w_d, b_d, w_d0, b_d0, w_d1, b_d1, w_d2, b_d2, out);
}